// Round 1
// baseline (2102.350 us; speedup 1.0000x reference)
//
#include <hip/hip_runtime.h>

#define BATCH  4
#define SLEN   2048
#define DMODEL 2048
#define NQ     32
#define NKV    8
#define GRP    4
#define DH     64
#define KVDIM  (NKV * DH)   // 512

// ---------------------------------------------------------------------------
// Kernel 1: pre-sum W_Q over each group of 4 heads.
// Reference sums the g axis in the scores einsum, so effective W_Q per kv-head
// is the sum of its 4 group heads. wqs layout: [n_kv][d_model][d_head].
// ---------------------------------------------------------------------------
__global__ __launch_bounds__(256) void k_sum_wq(const float* __restrict__ wq,
                                                float* __restrict__ wqs) {
    const int per_head = DMODEL * DH;           // 131072
    int i = blockIdx.x * 256 + threadIdx.x;     // over NKV*per_head = 1048576
    if (i < NKV * per_head) {
        int n = i / per_head;
        int rem = i - n * per_head;
        const float* base = wq + (size_t)(n * GRP) * per_head + rem;
        wqs[i] = base[0] + base[(size_t)per_head] + base[(size_t)2 * per_head]
               + base[(size_t)3 * per_head];
    }
}

// ---------------------------------------------------------------------------
// Kernel 2: fused QKV projection.
// C[M=8192][N=1536] = x[8192][2048] @ W, where W columns tile as
// 24 blocks of 64: blocks 0..7 -> W_Qsum heads, 8..15 -> W_K, 16..23 -> W_V.
// 64x64 tile, BK=16, 256 threads, 4x4 micro-tile per thread, fp32 vector FMA.
// Outputs qb/kb/vb in [b*s][n*64+h] layout (row stride 512).
// ---------------------------------------------------------------------------
__global__ __launch_bounds__(256) void k_qkv(const float* __restrict__ x,
                                             const float* __restrict__ wqs,
                                             const float* __restrict__ wk,
                                             const float* __restrict__ wv,
                                             float* __restrict__ qb,
                                             float* __restrict__ kb,
                                             float* __restrict__ vb) {
    __shared__ float As[64][17];   // [m][k], +1 pad
    __shared__ float Bs[16][65];   // [k][n], +1 pad

    const int t   = threadIdx.x;
    const int bm  = blockIdx.x;          // 0..127  (M tiles)
    const int bn  = blockIdx.y;          // 0..23   (N tiles, 1 head each)
    const int mat = bn >> 3;             // 0=Q,1=K,2=V
    const int head = bn & 7;

    const float* w = (mat == 0 ? wqs : (mat == 1 ? wk : wv))
                   + (size_t)head * DMODEL * DH;         // [2048][64] row-major
    float* ob = (mat == 0 ? qb : (mat == 1 ? kb : vb));

    const int a_row = t >> 2, a_col = (t & 3) << 2;   // A: 64 rows x 16 k
    const int b_row = t >> 4, b_col = (t & 15) << 2;  // B: 16 k x 64 n
    const int ty = t >> 4, tx = t & 15;
    const int r0 = ty << 2, c0 = tx << 2;
    const size_t m_base = (size_t)bm * 64;

    float acc[4][4] = {};

    for (int k0 = 0; k0 < DMODEL; k0 += 16) {
        float4 av = *(const float4*)(x + (m_base + a_row) * DMODEL + k0 + a_col);
        float4 bv = *(const float4*)(w + (size_t)(k0 + b_row) * DH + b_col);
        As[a_row][a_col + 0] = av.x; As[a_row][a_col + 1] = av.y;
        As[a_row][a_col + 2] = av.z; As[a_row][a_col + 3] = av.w;
        Bs[b_row][b_col + 0] = bv.x; Bs[b_row][b_col + 1] = bv.y;
        Bs[b_row][b_col + 2] = bv.z; Bs[b_row][b_col + 3] = bv.w;
        __syncthreads();
#pragma unroll
        for (int kk = 0; kk < 16; ++kk) {
            float a[4], bb[4];
#pragma unroll
            for (int i = 0; i < 4; ++i) a[i] = As[r0 + i][kk];
#pragma unroll
            for (int j = 0; j < 4; ++j) bb[j] = Bs[kk][c0 + j];
#pragma unroll
            for (int i = 0; i < 4; ++i)
#pragma unroll
                for (int j = 0; j < 4; ++j) acc[i][j] += a[i] * bb[j];
        }
        __syncthreads();
    }

#pragma unroll
    for (int i = 0; i < 4; ++i) {
        float* o = ob + (m_base + r0 + i) * KVDIM + head * DH + c0;
        o[0] = acc[i][0]; o[1] = acc[i][1]; o[2] = acc[i][2]; o[3] = acc[i][3];
    }
}

// ---------------------------------------------------------------------------
// Kernel 3: flash-style causal attention (fp32, vector ALU).
// Block = 256 threads handles one (b, n, 64-row q-tile); iterates k-tiles <= q-tile.
// S tile 64x64 via 4x4 micro-tiles; online softmax with LDS row reductions;
// V reuses the K LDS buffer. Masked scores = -100000.0f (reference IGNORE).
// ---------------------------------------------------------------------------
__global__ __launch_bounds__(256) void k_attn(const float* __restrict__ qb,
                                              const float* __restrict__ kb,
                                              const float* __restrict__ vb,
                                              float* __restrict__ zb) {
    __shared__ float Qs[64][65];
    __shared__ float KVs[64][65];
    __shared__ float Ps[64][65];
    __shared__ float red[64][17];
    __shared__ float rowm[64], rowl[64], newm[64], alph[64];

    const int t  = threadIdx.x;
    const int qt = blockIdx.x;   // 0..31
    const int n  = blockIdx.y;   // 0..7
    const int b  = blockIdx.z;   // 0..3
    const int ty = t >> 4, tx = t & 15;
    const int r0 = ty << 2, c0 = tx << 2;

    // load Q tile [64][64]
    for (int i = t; i < 64 * 16; i += 256) {
        int row = i >> 4, h4 = (i & 15) << 2;
        const float4 v = *(const float4*)(qb +
            ((size_t)(b * SLEN + qt * 64 + row) * NKV + n) * DH + h4);
        Qs[row][h4 + 0] = v.x; Qs[row][h4 + 1] = v.y;
        Qs[row][h4 + 2] = v.z; Qs[row][h4 + 3] = v.w;
    }
    if (t < 64) { rowm[t] = -3.0e38f; rowl[t] = 0.0f; }
    float Ot[4][4] = {};
    __syncthreads();

    for (int kt = 0; kt <= qt; ++kt) {
        // load K tile
        for (int i = t; i < 64 * 16; i += 256) {
            int row = i >> 4, h4 = (i & 15) << 2;
            const float4 v = *(const float4*)(kb +
                ((size_t)(b * SLEN + kt * 64 + row) * NKV + n) * DH + h4);
            KVs[row][h4 + 0] = v.x; KVs[row][h4 + 1] = v.y;
            KVs[row][h4 + 2] = v.z; KVs[row][h4 + 3] = v.w;
        }
        __syncthreads();

        // S = (Q @ K^T) / 8, causal mask
        float s[4][4] = {};
#pragma unroll 8
        for (int h = 0; h < 64; ++h) {
            float a[4], kv[4];
#pragma unroll
            for (int i = 0; i < 4; ++i) a[i] = Qs[r0 + i][h];
#pragma unroll
            for (int j = 0; j < 4; ++j) kv[j] = KVs[c0 + j][h];
#pragma unroll
            for (int i = 0; i < 4; ++i)
#pragma unroll
                for (int j = 0; j < 4; ++j) s[i][j] += a[i] * kv[j];
        }
#pragma unroll
        for (int i = 0; i < 4; ++i) {
            int qg = qt * 64 + r0 + i;
#pragma unroll
            for (int j = 0; j < 4; ++j) {
                int kg = kt * 64 + c0 + j;
                s[i][j] *= 0.125f;
                if (kg > qg) s[i][j] = -100000.0f;   // reference IGNORE
            }
        }

        // partial row max
#pragma unroll
        for (int i = 0; i < 4; ++i) {
            float pm = fmaxf(fmaxf(s[i][0], s[i][1]), fmaxf(s[i][2], s[i][3]));
            red[r0 + i][tx] = pm;
        }
        __syncthreads();
        if (t < 64) {
            float mp = red[t][0];
#pragma unroll
            for (int j2 = 1; j2 < 16; ++j2) mp = fmaxf(mp, red[t][j2]);
            float nm = fmaxf(rowm[t], mp);
            newm[t] = nm;
            alph[t] = __expf(rowm[t] - nm);
            rowm[t] = nm;
        }
        __syncthreads();

        // P = exp(S - newm), partial row sums, rescale O
#pragma unroll
        for (int i = 0; i < 4; ++i) {
            float nm = newm[r0 + i];
            float a  = alph[r0 + i];
            float ps = 0.0f;
#pragma unroll
            for (int j = 0; j < 4; ++j) {
                float p = __expf(s[i][j] - nm);
                Ps[r0 + i][c0 + j] = p;
                ps += p;
                Ot[i][j] *= a;
            }
            red[r0 + i][tx] = ps;
        }
        __syncthreads();
        if (t < 64) {
            float rs = 0.0f;
#pragma unroll
            for (int j2 = 0; j2 < 16; ++j2) rs += red[t][j2];
            rowl[t] = rowl[t] * alph[t] + rs;
        }
        // load V tile (overwrites KVs — all K reads finished before prior syncs)
        for (int i = t; i < 64 * 16; i += 256) {
            int row = i >> 4, h4 = (i & 15) << 2;
            const float4 v = *(const float4*)(vb +
                ((size_t)(b * SLEN + kt * 64 + row) * NKV + n) * DH + h4);
            KVs[row][h4 + 0] = v.x; KVs[row][h4 + 1] = v.y;
            KVs[row][h4 + 2] = v.z; KVs[row][h4 + 3] = v.w;
        }
        __syncthreads();

        // O += P @ V
#pragma unroll 8
        for (int k2 = 0; k2 < 64; ++k2) {
            float p[4], vv[4];
#pragma unroll
            for (int i = 0; i < 4; ++i) p[i] = Ps[r0 + i][k2];
#pragma unroll
            for (int j = 0; j < 4; ++j) vv[j] = KVs[k2][c0 + j];
#pragma unroll
            for (int i = 0; i < 4; ++i)
#pragma unroll
                for (int j = 0; j < 4; ++j) Ot[i][j] += p[i] * vv[j];
        }
        __syncthreads();
    }

    // normalize and write z[b][q][n][h]
#pragma unroll
    for (int i = 0; i < 4; ++i) {
        float inv = 1.0f / rowl[r0 + i];
#pragma unroll
        for (int j = 0; j < 4; ++j) {
            zb[((size_t)(b * SLEN + qt * 64 + r0 + i) * NKV + n) * DH + c0 + j] =
                Ot[i][j] * inv;
        }
    }
}

// ---------------------------------------------------------------------------
// Kernel 4: output projection.
// out[8192][2048] = z[8192][512] @ W_O (flat [512][2048] row-major).
// Same tiling as k_qkv.
// ---------------------------------------------------------------------------
__global__ __launch_bounds__(256) void k_out(const float* __restrict__ zb,
                                             const float* __restrict__ wo,
                                             float* __restrict__ out) {
    __shared__ float As[64][17];
    __shared__ float Bs[16][65];

    const int t  = threadIdx.x;
    const int bm = blockIdx.x;   // 0..127
    const int bn = blockIdx.y;   // 0..31
    const int a_row = t >> 2, a_col = (t & 3) << 2;
    const int b_row = t >> 4, b_col = (t & 15) << 2;
    const int ty = t >> 4, tx = t & 15;
    const int r0 = ty << 2, c0 = tx << 2;
    const size_t m_base = (size_t)bm * 64;
    const int n0 = bn * 64;

    float acc[4][4] = {};

    for (int k0 = 0; k0 < KVDIM; k0 += 16) {
        float4 av = *(const float4*)(zb + (m_base + a_row) * KVDIM + k0 + a_col);
        float4 bv = *(const float4*)(wo + (size_t)(k0 + b_row) * DMODEL + n0 + b_col);
        As[a_row][a_col + 0] = av.x; As[a_row][a_col + 1] = av.y;
        As[a_row][a_col + 2] = av.z; As[a_row][a_col + 3] = av.w;
        Bs[b_row][b_col + 0] = bv.x; Bs[b_row][b_col + 1] = bv.y;
        Bs[b_row][b_col + 2] = bv.z; Bs[b_row][b_col + 3] = bv.w;
        __syncthreads();
#pragma unroll
        for (int kk = 0; kk < 16; ++kk) {
            float a[4], bb[4];
#pragma unroll
            for (int i = 0; i < 4; ++i) a[i] = As[r0 + i][kk];
#pragma unroll
            for (int j = 0; j < 4; ++j) bb[j] = Bs[kk][c0 + j];
#pragma unroll
            for (int i = 0; i < 4; ++i)
#pragma unroll
                for (int j = 0; j < 4; ++j) acc[i][j] += a[i] * bb[j];
        }
        __syncthreads();
    }

#pragma unroll
    for (int i = 0; i < 4; ++i) {
        float* o = out + (m_base + r0 + i) * DMODEL + n0 + c0;
        o[0] = acc[i][0]; o[1] = acc[i][1]; o[2] = acc[i][2]; o[3] = acc[i][3];
    }
}

// ---------------------------------------------------------------------------
// Launch. Workspace layout (floats):
//   wqs : NKV*DMODEL*DH          = 1,048,576   ( 4 MB)
//   qb  : BATCH*SLEN*NKV*DH      = 4,194,304   (16 MB)
//   kb  : 4,194,304
//   vb  : 4,194,304
//   zb  : 4,194,304
// total = 17,825,792 floats = 71.3 MB
// ---------------------------------------------------------------------------
extern "C" void kernel_launch(void* const* d_in, const int* in_sizes, int n_in,
                              void* d_out, int out_size, void* d_ws, size_t ws_size,
                              hipStream_t stream) {
    const float* x  = (const float*)d_in[0];
    const float* wq = (const float*)d_in[1];
    const float* wk = (const float*)d_in[2];
    const float* wv = (const float*)d_in[3];
    const float* wo = (const float*)d_in[4];
    float* out = (float*)d_out;

    float* ws  = (float*)d_ws;
    float* wqs = ws;
    float* qb  = wqs + (size_t)NKV * DMODEL * DH;
    float* kb  = qb + (size_t)BATCH * SLEN * NKV * DH;
    float* vb  = kb + (size_t)BATCH * SLEN * NKV * DH;
    float* zb  = vb + (size_t)BATCH * SLEN * NKV * DH;

    k_sum_wq<<<dim3((NKV * DMODEL * DH + 255) / 256), 256, 0, stream>>>(wq, wqs);
    k_qkv<<<dim3(128, 24), 256, 0, stream>>>(x, wqs, wk, wv, qb, kb, vb);
    k_attn<<<dim3(32, NKV, BATCH), 256, 0, stream>>>(qb, kb, vb, zb);
    k_out<<<dim3(128, 32), 256, 0, stream>>>(zb, wo, out);
}

// Round 2
// 1331.991 us; speedup vs baseline: 1.5784x; 1.5784x over previous
//
#include <hip/hip_runtime.h>

#define BATCH  4
#define SLEN   2048
#define DMODEL 2048
#define NKV    8
#define GRP    4
#define DH     64
#define QKV    1536
#define KVDIM  512

// ---------------------------------------------------------------------------
// Kernel 1: pack weights into Wcat[d_model][1536].
// cols 0..511: sum_g W_Q (group-summed, per reference's g-summing einsum),
// cols 512..1023: W_K, cols 1024..1535: W_V.  col = mat*512 + n*64 + h.
// ---------------------------------------------------------------------------
__global__ __launch_bounds__(256) void k_pack(const float* __restrict__ wq,
                                              const float* __restrict__ wk,
                                              const float* __restrict__ wv,
                                              float* __restrict__ wcat) {
    int i = blockIdx.x * 256 + threadIdx.x;   // over DMODEL*QKV
    if (i >= DMODEL * QKV) return;
    int d = i / QKV, c = i - d * QKV;
    int mat = c >> 9, rem = c & 511;
    int n = rem >> 6, h = rem & 63;
    float val;
    if (mat == 0) {
        val = 0.0f;
#pragma unroll
        for (int g = 0; g < GRP; ++g)
            val += wq[((size_t)(n * GRP + g) * DMODEL + d) * DH + h];
    } else if (mat == 1) {
        val = wk[((size_t)n * DMODEL + d) * DH + h];
    } else {
        val = wv[((size_t)n * DMODEL + d) * DH + h];
    }
    wcat[(size_t)d * QKV + c] = val;
}

// ---------------------------------------------------------------------------
// Kernel 2: fp32 GEMM, C[M][N] = A[M][K] @ B[K][N].
// 128x128 tile, BK=16, 256 threads, 8x8 micro-tile.
// A staged TRANSPOSED in LDS (AsT[k][m], pad 132 -> conflict-free scalar
// stores, b128 reads); B staged row-major (b128 stores and reads).
// Inner loop per kk: 4x ds_read_b128 + 64 v_fmac -> FMA-issue-bound.
// ---------------------------------------------------------------------------
__global__ __launch_bounds__(256) void k_gemm(const float* __restrict__ A,
                                              const float* __restrict__ B,
                                              float* __restrict__ C,
                                              int M, int N, int K) {
    __shared__ float AsT[16][132];
    __shared__ float Bs[16][132];

    const int t  = threadIdx.x;
    const int m0 = blockIdx.x * 128;
    const int n0 = blockIdx.y * 128;
    const int ty = t >> 4, tx = t & 15;
    const int ar = t >> 2;            // A row within half-tile (0..63)
    const int ak = (t & 3) << 2;      // A k-quad base (0,4,8,12)
    const int bk = t >> 5;            // B k-row (0..7; +8 for second)
    const int bc = (t & 31) << 2;     // B col base (0..124)

    float acc[8][8] = {};

    const float* Ap0 = A + (size_t)(m0 + ar) * K + ak;
    const float* Ap1 = A + (size_t)(m0 + 64 + ar) * K + ak;
    const float* Bp0 = B + (size_t)bk * N + n0 + bc;
    const float* Bp1 = B + (size_t)(bk + 8) * N + n0 + bc;

    for (int k0 = 0; k0 < K; k0 += 16) {
        float4 a0 = *(const float4*)(Ap0 + k0);
        float4 a1 = *(const float4*)(Ap1 + k0);
        float4 b0 = *(const float4*)(Bp0 + (size_t)k0 * N);
        float4 b1 = *(const float4*)(Bp1 + (size_t)k0 * N);
        __syncthreads();   // previous tile fully consumed
        AsT[ak + 0][ar] = a0.x; AsT[ak + 1][ar] = a0.y;
        AsT[ak + 2][ar] = a0.z; AsT[ak + 3][ar] = a0.w;
        AsT[ak + 0][64 + ar] = a1.x; AsT[ak + 1][64 + ar] = a1.y;
        AsT[ak + 2][64 + ar] = a1.z; AsT[ak + 3][64 + ar] = a1.w;
        *(float4*)&Bs[bk][bc]     = b0;
        *(float4*)&Bs[bk + 8][bc] = b1;
        __syncthreads();   // tile visible
#pragma unroll
        for (int kk = 0; kk < 16; ++kk) {
            float4 x0 = *(const float4*)&AsT[kk][ty * 4];
            float4 x1 = *(const float4*)&AsT[kk][64 + ty * 4];
            float4 y0 = *(const float4*)&Bs[kk][tx * 4];
            float4 y1 = *(const float4*)&Bs[kk][64 + tx * 4];
            float xa[8] = {x0.x, x0.y, x0.z, x0.w, x1.x, x1.y, x1.z, x1.w};
            float yb[8] = {y0.x, y0.y, y0.z, y0.w, y1.x, y1.y, y1.z, y1.w};
#pragma unroll
            for (int i = 0; i < 8; ++i)
#pragma unroll
                for (int j = 0; j < 8; ++j) acc[i][j] += xa[i] * yb[j];
        }
    }

#pragma unroll
    for (int hf = 0; hf < 2; ++hf)
#pragma unroll
        for (int i = 0; i < 4; ++i) {
            float* cp = C + (size_t)(m0 + hf * 64 + ty * 4 + i) * N + n0;
            *(float4*)(cp + tx * 4) =
                make_float4(acc[hf * 4 + i][0], acc[hf * 4 + i][1],
                            acc[hf * 4 + i][2], acc[hf * 4 + i][3]);
            *(float4*)(cp + 64 + tx * 4) =
                make_float4(acc[hf * 4 + i][4], acc[hf * 4 + i][5],
                            acc[hf * 4 + i][6], acc[hf * 4 + i][7]);
        }
}

// ---------------------------------------------------------------------------
// Kernel 3: flash-style causal attention (fp32 vector ALU), vectorized LDS.
// Q,K staged transposed ([h][row], pad 68 -> 2-way stores (free), b128 reads);
// V row-major; P staged transposed ([col][row], pad 72, b128 reads in PV).
// Block = 256 threads, one (b, n, 64-row q-tile); k-tiles <= q-tile.
// ---------------------------------------------------------------------------
__global__ __launch_bounds__(256) void k_attn(const float* __restrict__ qkvb,
                                              float* __restrict__ zb) {
    __shared__ float Qt[64][68];
    __shared__ float Kt[64][68];
    __shared__ float Vs[64][68];
    __shared__ float Pt[64][72];
    __shared__ float red[64][17];
    __shared__ float rowm[64], rowl[64], newm[64], alph[64];

    const int t  = threadIdx.x;
    const int qt = blockIdx.x;   // 0..31
    const int n  = blockIdx.y;   // 0..7
    const int b  = blockIdx.z;   // 0..3
    const int ty = t >> 4, tx = t & 15;
    const int r0 = ty << 2, c0 = tx << 2;
    const int lrow = t >> 2;           // 0..63
    const int lq   = (t & 3) << 2;     // base h-quad

    const size_t qrow0 = (size_t)(b * SLEN + qt * 64);

    // load Q tile transposed: Qt[h][row]
#pragma unroll
    for (int it = 0; it < 4; ++it) {
        int h4 = lq + it * 16;
        const float4 v = *(const float4*)(qkvb + (qrow0 + lrow) * QKV + n * 64 + h4);
        Qt[h4 + 0][lrow] = v.x; Qt[h4 + 1][lrow] = v.y;
        Qt[h4 + 2][lrow] = v.z; Qt[h4 + 3][lrow] = v.w;
    }
    if (t < 64) { rowm[t] = -3.0e38f; rowl[t] = 0.0f; }
    float Ot[4][4] = {};

    for (int kt = 0; kt <= qt; ++kt) {
        const size_t krow0 = (size_t)(b * SLEN + kt * 64);
        __syncthreads();   // prev iter's Kt/Vs reads done (also covers Q init)
#pragma unroll
        for (int it = 0; it < 4; ++it) {
            int h4 = lq + it * 16;
            const float4 kv = *(const float4*)(qkvb + (krow0 + lrow) * QKV + KVDIM + n * 64 + h4);
            Kt[h4 + 0][lrow] = kv.x; Kt[h4 + 1][lrow] = kv.y;
            Kt[h4 + 2][lrow] = kv.z; Kt[h4 + 3][lrow] = kv.w;
            const float4 vv = *(const float4*)(qkvb + (krow0 + lrow) * QKV + 2 * KVDIM + n * 64 + h4);
            *(float4*)&Vs[lrow][h4] = vv;
        }
        __syncthreads();

        // S = (Q @ K^T) / 8 with causal mask
        float s[4][4] = {};
#pragma unroll 8
        for (int h = 0; h < 64; ++h) {
            float4 qv = *(const float4*)&Qt[h][r0];
            float4 kv = *(const float4*)&Kt[h][c0];
            float qa[4] = {qv.x, qv.y, qv.z, qv.w};
            float ka[4] = {kv.x, kv.y, kv.z, kv.w};
#pragma unroll
            for (int i = 0; i < 4; ++i)
#pragma unroll
                for (int j = 0; j < 4; ++j) s[i][j] += qa[i] * ka[j];
        }
#pragma unroll
        for (int i = 0; i < 4; ++i) {
            int qg = qt * 64 + r0 + i;
#pragma unroll
            for (int j = 0; j < 4; ++j) {
                int kg = kt * 64 + c0 + j;
                s[i][j] *= 0.125f;
                if (kg > qg) s[i][j] = -100000.0f;   // reference IGNORE
            }
        }

        // online softmax: row max
#pragma unroll
        for (int i = 0; i < 4; ++i)
            red[r0 + i][tx] = fmaxf(fmaxf(s[i][0], s[i][1]), fmaxf(s[i][2], s[i][3]));
        __syncthreads();
        if (t < 64) {
            float mp = red[t][0];
#pragma unroll
            for (int j2 = 1; j2 < 16; ++j2) mp = fmaxf(mp, red[t][j2]);
            float nm = fmaxf(rowm[t], mp);
            newm[t] = nm;
            alph[t] = __expf(rowm[t] - nm);
            rowm[t] = nm;
        }
        __syncthreads();

        // P = exp(S - newm) -> Pt[col][row]; rescale O; partial row sums
#pragma unroll
        for (int i = 0; i < 4; ++i) {
            float nm = newm[r0 + i];
            float a  = alph[r0 + i];
            float ps = 0.0f;
#pragma unroll
            for (int j = 0; j < 4; ++j) {
                float p = __expf(s[i][j] - nm);
                Pt[c0 + j][r0 + i] = p;
                ps += p;
                Ot[i][j] *= a;
            }
            red[r0 + i][tx] = ps;
        }
        __syncthreads();
        if (t < 64) {
            float rs = 0.0f;
#pragma unroll
            for (int j2 = 0; j2 < 16; ++j2) rs += red[t][j2];
            rowl[t] = rowl[t] * alph[t] + rs;
        }

        // O += P @ V  (b128 reads of both operands)
#pragma unroll 8
        for (int k2 = 0; k2 < 64; ++k2) {
            float4 pv = *(const float4*)&Pt[k2][r0];
            float4 vv = *(const float4*)&Vs[k2][c0];
            float pa[4] = {pv.x, pv.y, pv.z, pv.w};
            float va[4] = {vv.x, vv.y, vv.z, vv.w};
#pragma unroll
            for (int i = 0; i < 4; ++i)
#pragma unroll
                for (int j = 0; j < 4; ++j) Ot[i][j] += pa[i] * va[j];
        }
    }

    // normalize, write z[b*s][n*64+h]
#pragma unroll
    for (int i = 0; i < 4; ++i) {
        float inv = 1.0f / rowl[r0 + i];
        *(float4*)(zb + (qrow0 + r0 + i) * KVDIM + n * 64 + c0) =
            make_float4(Ot[i][0] * inv, Ot[i][1] * inv, Ot[i][2] * inv, Ot[i][3] * inv);
    }
}

// ---------------------------------------------------------------------------
// Launch. Workspace (floats):
//   region0 (reused): wcat [2048*1536]=12MB, later zb [8192*512]=16MB
//   qkvb: 8192*1536 = 48MB
// total 64 MB.
// ---------------------------------------------------------------------------
extern "C" void kernel_launch(void* const* d_in, const int* in_sizes, int n_in,
                              void* d_out, int out_size, void* d_ws, size_t ws_size,
                              hipStream_t stream) {
    const float* x  = (const float*)d_in[0];
    const float* wq = (const float*)d_in[1];
    const float* wk = (const float*)d_in[2];
    const float* wv = (const float*)d_in[3];
    const float* wo = (const float*)d_in[4];
    float* out = (float*)d_out;

    float* ws   = (float*)d_ws;
    float* wcat = ws;                                   // 3,145,728 floats
    float* zb   = ws;                                   // reuses region0 after GEMM1
    float* qkvb = ws + (size_t)BATCH * SLEN * KVDIM;    // offset 4,194,304 floats

    k_pack<<<dim3((DMODEL * QKV + 255) / 256), 256, 0, stream>>>(wq, wk, wv, wcat);
    k_gemm<<<dim3(64, 12), 256, 0, stream>>>(x, wcat, qkvb,
                                             BATCH * SLEN, QKV, DMODEL);
    k_attn<<<dim3(32, NKV, BATCH), 256, 0, stream>>>(qkvb, zb);
    k_gemm<<<dim3(64, 16), 256, 0, stream>>>(zb, wo, out,
                                             BATCH * SLEN, DMODEL, KVDIM);
}

// Round 3
// 818.375 us; speedup vs baseline: 2.5689x; 1.6276x over previous
//
#include <hip/hip_runtime.h>

typedef __attribute__((ext_vector_type(8))) short short8;
typedef __attribute__((ext_vector_type(4))) float f32x4;

#define BATCH  4
#define SLEN   2048
#define DMODEL 2048
#define NKV    8
#define GRP    4
#define DH     64
#define QKV    1536
#define KVDIM  512
#define MROWS  (BATCH * SLEN)   // 8192

// ---- bf16 helpers (RNE) ----------------------------------------------------
__device__ __forceinline__ unsigned short f2bf(float f) {
    unsigned u = __float_as_uint(f);
    u += 0x7FFFu + ((u >> 16) & 1u);
    return (unsigned short)(u >> 16);
}
__device__ __forceinline__ float bf2f(unsigned short h) {
    return __uint_as_float(((unsigned)h) << 16);
}

// ---- async global->LDS, 16B per lane ---------------------------------------
__device__ __forceinline__ void gl16(const void* g, void* l) {
    __builtin_amdgcn_global_load_lds(
        (const __attribute__((address_space(1))) void*)g,
        (__attribute__((address_space(3))) void*)l, 16, 0, 0);
}

// ---------------------------------------------------------------------------
// Kernel 1: pack weights into Wcat[d_model][1536] (fp32).
// cols 0..511: sum_g W_Q (reference sums g in the scores einsum),
// 512..1023: W_K, 1024..1535: W_V.  col = mat*512 + n*64 + h.
// ---------------------------------------------------------------------------
__global__ __launch_bounds__(256) void k_pack(const float* __restrict__ wq,
                                              const float* __restrict__ wk,
                                              const float* __restrict__ wv,
                                              float* __restrict__ wcat) {
    int i = blockIdx.x * 256 + threadIdx.x;
    if (i >= DMODEL * QKV) return;
    int d = i / QKV, c = i - d * QKV;
    int mat = c >> 9, rem = c & 511;
    int n = rem >> 6, h = rem & 63;
    float val;
    if (mat == 0) {
        val = 0.0f;
#pragma unroll
        for (int g = 0; g < GRP; ++g)
            val += wq[((size_t)(n * GRP + g) * DMODEL + d) * DH + h];
    } else if (mat == 1) {
        val = wk[((size_t)n * DMODEL + d) * DH + h];
    } else {
        val = wv[((size_t)n * DMODEL + d) * DH + h];
    }
    wcat[(size_t)d * QKV + c] = val;
}

// ---------------------------------------------------------------------------
// Kernel 2: transpose + split-convert. in fp32 [R][C] -> hi/lo ushort [C][R].
// 64x64 LDS tile, coalesced both sides, conflict-free (pad 65).
// ---------------------------------------------------------------------------
__global__ __launch_bounds__(256) void k_transconv(const float* __restrict__ in,
                                                   unsigned short* __restrict__ hi,
                                                   unsigned short* __restrict__ lo,
                                                   int R, int C) {
    __shared__ float T[64][65];
    const int r0 = blockIdx.x * 64, c0 = blockIdx.y * 64;
    const int tr = threadIdx.x >> 6, tc = threadIdx.x & 63;
#pragma unroll
    for (int i = 0; i < 16; ++i)
        T[tr + i * 4][tc] = in[(size_t)(r0 + tr + i * 4) * C + c0 + tc];
    __syncthreads();
    const int rr = tc;
#pragma unroll
    for (int i = 0; i < 16; ++i) {
        int cc = tr + i * 4;
        float v = T[rr][cc];
        unsigned short h = f2bf(v);
        hi[(size_t)(c0 + cc) * R + r0 + rr] = h;
        lo[(size_t)(c0 + cc) * R + r0 + rr] = f2bf(v - bf2f(h));
    }
}

// ---------------------------------------------------------------------------
// Kernel 3: elementwise split-convert fp32 -> hi/lo bf16 (as ushort).
// ---------------------------------------------------------------------------
__global__ __launch_bounds__(256) void k_conv(const float* __restrict__ in,
                                              unsigned short* __restrict__ hi,
                                              unsigned short* __restrict__ lo,
                                              int n4) {
    int i = blockIdx.x * 256 + threadIdx.x;
    if (i >= n4) return;
    float4 v = ((const float4*)in)[i];
    ushort4 h, l;
    h.x = f2bf(v.x); l.x = f2bf(v.x - bf2f(h.x));
    h.y = f2bf(v.y); l.y = f2bf(v.y - bf2f(h.y));
    h.z = f2bf(v.z); l.z = f2bf(v.z - bf2f(h.z));
    h.w = f2bf(v.w); l.w = f2bf(v.w - bf2f(h.w));
    ((ushort4*)hi)[i] = h;
    ((ushort4*)lo)[i] = l;
}

// ---------------------------------------------------------------------------
// Kernel 4: bf16x3 split-precision MFMA GEMM.  C[M][N] = A[M][K] @ B[K][N].
// A given as hi/lo bf16 [M][K]; B given PRE-TRANSPOSED hi/lo bf16 [N][K].
// 128x128 tile, BK=32, 256 thr (4 waves, 2x2 of 64x64), 16x16x32 bf16 MFMA.
// Per K-step: 8x global_load_lds(16B) stage, 16x ds_read_b128 frags,
// 48 MFMA (hi*hi + lo*hi + hi*lo), fp32 accum.  M%128==N%128==K%32==0.
// ---------------------------------------------------------------------------
__global__ __launch_bounds__(256) void k_gemm_b3(
        const unsigned short* __restrict__ Ahg, const unsigned short* __restrict__ Alg,
        const unsigned short* __restrict__ Bhg, const unsigned short* __restrict__ Blg,
        float* __restrict__ C, int M, int N, int K) {
    __shared__ unsigned short Ah[128 * 32], Al[128 * 32];
    __shared__ unsigned short Bh[128 * 32], Bl[128 * 32];

    const int t  = threadIdx.x;
    const int m0 = blockIdx.x * 128, n0 = blockIdx.y * 128;
    const int w  = t >> 6, l = t & 63;
    const int wm = (w >> 1) * 64, wn = (w & 1) * 64;
    const int r  = l & 15, q = l >> 4;

    const int srow = t >> 2;            // staging row 0..63 (+64 second round)
    const int skq  = (t & 3) * 8;       // k element offset (8 bf16 = 16B)
    const int soff = srow * 32 + skq;   // LDS element offset, linear in t

    f32x4 acc[4][4] = {};

    for (int k0 = 0; k0 < K; k0 += 32) {
        __syncthreads();   // previous tile fully consumed
        gl16(Ahg + (size_t)(m0 + srow) * K + k0 + skq,      &Ah[soff]);
        gl16(Ahg + (size_t)(m0 + 64 + srow) * K + k0 + skq, &Ah[soff + 64 * 32]);
        gl16(Alg + (size_t)(m0 + srow) * K + k0 + skq,      &Al[soff]);
        gl16(Alg + (size_t)(m0 + 64 + srow) * K + k0 + skq, &Al[soff + 64 * 32]);
        gl16(Bhg + (size_t)(n0 + srow) * K + k0 + skq,      &Bh[soff]);
        gl16(Bhg + (size_t)(n0 + 64 + srow) * K + k0 + skq, &Bh[soff + 64 * 32]);
        gl16(Blg + (size_t)(n0 + srow) * K + k0 + skq,      &Bl[soff]);
        gl16(Blg + (size_t)(n0 + 64 + srow) * K + k0 + skq, &Bl[soff + 64 * 32]);
        __syncthreads();   // compiler drains vmcnt before barrier

        short8 ah[4], al[4], bh[4], bl[4];
#pragma unroll
        for (int i = 0; i < 4; ++i) {
            ah[i] = *(const short8*)&Ah[(wm + i * 16 + r) * 32 + q * 8];
            al[i] = *(const short8*)&Al[(wm + i * 16 + r) * 32 + q * 8];
            bh[i] = *(const short8*)&Bh[(wn + i * 16 + r) * 32 + q * 8];
            bl[i] = *(const short8*)&Bl[(wn + i * 16 + r) * 32 + q * 8];
        }
#pragma unroll
        for (int i = 0; i < 4; ++i)
#pragma unroll
            for (int j = 0; j < 4; ++j) {
                acc[i][j] = __builtin_amdgcn_mfma_f32_16x16x32_bf16(ah[i], bh[j], acc[i][j], 0, 0, 0);
                acc[i][j] = __builtin_amdgcn_mfma_f32_16x16x32_bf16(al[i], bh[j], acc[i][j], 0, 0, 0);
                acc[i][j] = __builtin_amdgcn_mfma_f32_16x16x32_bf16(ah[i], bl[j], acc[i][j], 0, 0, 0);
            }
    }

    // C/D layout: col = lane&15, row = (lane>>4)*4 + reg   [m89-verified]
#pragma unroll
    for (int i = 0; i < 4; ++i)
#pragma unroll
        for (int j = 0; j < 4; ++j) {
            int col = n0 + wn + j * 16 + r;
            size_t rowb = (size_t)(m0 + wm + i * 16 + q * 4);
#pragma unroll
            for (int e = 0; e < 4; ++e)
                C[(rowb + e) * N + col] = acc[i][j][e];
        }
}

// ---------------------------------------------------------------------------
// Kernel 5: flash-style causal attention (fp32 vector ALU) — unchanged R2.
// ---------------------------------------------------------------------------
__global__ __launch_bounds__(256) void k_attn(const float* __restrict__ qkvb,
                                              float* __restrict__ zb) {
    __shared__ float Qt[64][68];
    __shared__ float Kt[64][68];
    __shared__ float Vs[64][68];
    __shared__ float Pt[64][72];
    __shared__ float red[64][17];
    __shared__ float rowm[64], rowl[64], newm[64], alph[64];

    const int t  = threadIdx.x;
    const int qt = blockIdx.x;
    const int n  = blockIdx.y;
    const int b  = blockIdx.z;
    const int ty = t >> 4, tx = t & 15;
    const int r0 = ty << 2, c0 = tx << 2;
    const int lrow = t >> 2;
    const int lq   = (t & 3) << 2;

    const size_t qrow0 = (size_t)(b * SLEN + qt * 64);

#pragma unroll
    for (int it = 0; it < 4; ++it) {
        int h4 = lq + it * 16;
        const float4 v = *(const float4*)(qkvb + (qrow0 + lrow) * QKV + n * 64 + h4);
        Qt[h4 + 0][lrow] = v.x; Qt[h4 + 1][lrow] = v.y;
        Qt[h4 + 2][lrow] = v.z; Qt[h4 + 3][lrow] = v.w;
    }
    if (t < 64) { rowm[t] = -3.0e38f; rowl[t] = 0.0f; }
    float Ot[4][4] = {};

    for (int kt = 0; kt <= qt; ++kt) {
        const size_t krow0 = (size_t)(b * SLEN + kt * 64);
        __syncthreads();
#pragma unroll
        for (int it = 0; it < 4; ++it) {
            int h4 = lq + it * 16;
            const float4 kv = *(const float4*)(qkvb + (krow0 + lrow) * QKV + KVDIM + n * 64 + h4);
            Kt[h4 + 0][lrow] = kv.x; Kt[h4 + 1][lrow] = kv.y;
            Kt[h4 + 2][lrow] = kv.z; Kt[h4 + 3][lrow] = kv.w;
            const float4 vv = *(const float4*)(qkvb + (krow0 + lrow) * QKV + 2 * KVDIM + n * 64 + h4);
            *(float4*)&Vs[lrow][h4] = vv;
        }
        __syncthreads();

        float s[4][4] = {};
#pragma unroll 8
        for (int h = 0; h < 64; ++h) {
            float4 qv = *(const float4*)&Qt[h][r0];
            float4 kv = *(const float4*)&Kt[h][c0];
            float qa[4] = {qv.x, qv.y, qv.z, qv.w};
            float ka[4] = {kv.x, kv.y, kv.z, kv.w};
#pragma unroll
            for (int i = 0; i < 4; ++i)
#pragma unroll
                for (int j = 0; j < 4; ++j) s[i][j] += qa[i] * ka[j];
        }
#pragma unroll
        for (int i = 0; i < 4; ++i) {
            int qg = qt * 64 + r0 + i;
#pragma unroll
            for (int j = 0; j < 4; ++j) {
                int kg = kt * 64 + c0 + j;
                s[i][j] *= 0.125f;
                if (kg > qg) s[i][j] = -100000.0f;
            }
        }

#pragma unroll
        for (int i = 0; i < 4; ++i)
            red[r0 + i][tx] = fmaxf(fmaxf(s[i][0], s[i][1]), fmaxf(s[i][2], s[i][3]));
        __syncthreads();
        if (t < 64) {
            float mp = red[t][0];
#pragma unroll
            for (int j2 = 1; j2 < 16; ++j2) mp = fmaxf(mp, red[t][j2]);
            float nm = fmaxf(rowm[t], mp);
            newm[t] = nm;
            alph[t] = __expf(rowm[t] - nm);
            rowm[t] = nm;
        }
        __syncthreads();

#pragma unroll
        for (int i = 0; i < 4; ++i) {
            float nm = newm[r0 + i];
            float a  = alph[r0 + i];
            float ps = 0.0f;
#pragma unroll
            for (int j = 0; j < 4; ++j) {
                float p = __expf(s[i][j] - nm);
                Pt[c0 + j][r0 + i] = p;
                ps += p;
                Ot[i][j] *= a;
            }
            red[r0 + i][tx] = ps;
        }
        __syncthreads();
        if (t < 64) {
            float rs = 0.0f;
#pragma unroll
            for (int j2 = 0; j2 < 16; ++j2) rs += red[t][j2];
            rowl[t] = rowl[t] * alph[t] + rs;
        }

#pragma unroll 8
        for (int k2 = 0; k2 < 64; ++k2) {
            float4 pv = *(const float4*)&Pt[k2][r0];
            float4 vv = *(const float4*)&Vs[k2][c0];
            float pa[4] = {pv.x, pv.y, pv.z, pv.w};
            float va[4] = {vv.x, vv.y, vv.z, vv.w};
#pragma unroll
            for (int i = 0; i < 4; ++i)
#pragma unroll
                for (int j = 0; j < 4; ++j) Ot[i][j] += pa[i] * va[j];
        }
    }

#pragma unroll
    for (int i = 0; i < 4; ++i) {
        float inv = 1.0f / rowl[r0 + i];
        *(float4*)(zb + (qrow0 + r0 + i) * KVDIM + n * 64 + c0) =
            make_float4(Ot[i][0] * inv, Ot[i][1] * inv, Ot[i][2] * inv, Ot[i][3] * inv);
    }
}

// ---------------------------------------------------------------------------
// Launch. Workspace layout (128 MB total), stream-order reuse:
//   [0,64M):    xh(32M) xl(32M)        -> after gemm1: zb(16M) zh(8M) zl(8M)
//   [64M,112M): wcat fp32 (12M, dead before gemm1) then qkvb (48M)
//   [112M,124M): wcatT hi/lo (6M+6M)
//   [124M,128M): woT hi/lo (2M+2M)
// ---------------------------------------------------------------------------
extern "C" void kernel_launch(void* const* d_in, const int* in_sizes, int n_in,
                              void* d_out, int out_size, void* d_ws, size_t ws_size,
                              hipStream_t stream) {
    const float* x  = (const float*)d_in[0];
    const float* wq = (const float*)d_in[1];
    const float* wk = (const float*)d_in[2];
    const float* wv = (const float*)d_in[3];
    const float* wo = (const float*)d_in[4];
    float* out = (float*)d_out;

    char* w = (char*)d_ws;
    unsigned short* xh = (unsigned short*)(w);
    unsigned short* xl = (unsigned short*)(w + 33554432);
    float*          zb = (float*)(w);
    unsigned short* zh = (unsigned short*)(w + 16777216);
    unsigned short* zl = (unsigned short*)(w + 25165824);
    float*        wcat = (float*)(w + 67108864);
    float*        qkvb = (float*)(w + 67108864);
    unsigned short* wcatTh = (unsigned short*)(w + 117440512);
    unsigned short* wcatTl = (unsigned short*)(w + 117440512 + 6291456);
    unsigned short* woTh   = (unsigned short*)(w + 130023424);
    unsigned short* woTl   = (unsigned short*)(w + 130023424 + 2097152);

    k_pack<<<dim3((DMODEL * QKV + 255) / 256), 256, 0, stream>>>(wq, wk, wv, wcat);
    k_transconv<<<dim3(32, 24), 256, 0, stream>>>(wcat, wcatTh, wcatTl, DMODEL, QKV);
    k_transconv<<<dim3(8, 32), 256, 0, stream>>>(wo, woTh, woTl, KVDIM, DMODEL);
    k_conv<<<dim3(16384), 256, 0, stream>>>(x, xh, xl, MROWS * DMODEL / 4);
    k_gemm_b3<<<dim3(64, 12), 256, 0, stream>>>(xh, xl, wcatTh, wcatTl, qkvb,
                                                MROWS, QKV, DMODEL);
    k_attn<<<dim3(32, NKV, BATCH), 256, 0, stream>>>(qkvb, zb);
    k_conv<<<dim3(4096), 256, 0, stream>>>(zb, zh, zl, MROWS * KVDIM / 4);
    k_gemm_b3<<<dim3(64, 16), 256, 0, stream>>>(zh, zl, woTh, woTl, out,
                                                MROWS, DMODEL, KVDIM);
}

// Round 4
// 439.253 us; speedup vs baseline: 4.7862x; 1.8631x over previous
//
#include <hip/hip_runtime.h>

typedef __attribute__((ext_vector_type(8))) short short8;
typedef __attribute__((ext_vector_type(4))) short short4v;
typedef __attribute__((ext_vector_type(4))) float f32x4;

#define BATCH  4
#define SLEN   2048
#define DMODEL 2048
#define NKV    8
#define GRP    4
#define DH     64
#define QKV    1536
#define KVDIM  512
#define MROWS  (BATCH * SLEN)   // 8192

// ---- bf16 helpers (RNE) ----------------------------------------------------
__device__ __forceinline__ unsigned short f2bf(float f) {
    unsigned u = __float_as_uint(f);
    u += 0x7FFFu + ((u >> 16) & 1u);
    return (unsigned short)(u >> 16);
}
__device__ __forceinline__ float bf2f(unsigned short h) {
    return __uint_as_float(((unsigned)h) << 16);
}

// ---- async global->LDS, 16B per lane ---------------------------------------
__device__ __forceinline__ void gl16(const void* g, void* l) {
    __builtin_amdgcn_global_load_lds(
        (const __attribute__((address_space(1))) void*)g,
        (__attribute__((address_space(3))) void*)l, 16, 0, 0);
}

union U64S4 { unsigned long long u; short4v s; };

// ---------------------------------------------------------------------------
// Kernel 1: pack weights into Wcat[d_model][1536] (fp32).
// cols 0..511: sum_g W_Q (reference sums g in the scores einsum),
// 512..1023: W_K, 1024..1535: W_V.  col = mat*512 + n*64 + h.
// ---------------------------------------------------------------------------
__global__ __launch_bounds__(256) void k_pack(const float* __restrict__ wq,
                                              const float* __restrict__ wk,
                                              const float* __restrict__ wv,
                                              float* __restrict__ wcat) {
    int i = blockIdx.x * 256 + threadIdx.x;
    if (i >= DMODEL * QKV) return;
    int d = i / QKV, c = i - d * QKV;
    int mat = c >> 9, rem = c & 511;
    int n = rem >> 6, h = rem & 63;
    float val;
    if (mat == 0) {
        val = 0.0f;
#pragma unroll
        for (int g = 0; g < GRP; ++g)
            val += wq[((size_t)(n * GRP + g) * DMODEL + d) * DH + h];
    } else if (mat == 1) {
        val = wk[((size_t)n * DMODEL + d) * DH + h];
    } else {
        val = wv[((size_t)n * DMODEL + d) * DH + h];
    }
    wcat[(size_t)d * QKV + c] = val;
}

// ---------------------------------------------------------------------------
// Kernel 2: transpose + split-convert. in fp32 [R][C] -> hi/lo ushort [C][R].
// ---------------------------------------------------------------------------
__global__ __launch_bounds__(256) void k_transconv(const float* __restrict__ in,
                                                   unsigned short* __restrict__ hi,
                                                   unsigned short* __restrict__ lo,
                                                   int R, int C) {
    __shared__ float T[64][65];
    const int r0 = blockIdx.x * 64, c0 = blockIdx.y * 64;
    const int tr = threadIdx.x >> 6, tc = threadIdx.x & 63;
#pragma unroll
    for (int i = 0; i < 16; ++i)
        T[tr + i * 4][tc] = in[(size_t)(r0 + tr + i * 4) * C + c0 + tc];
    __syncthreads();
    const int rr = tc;
#pragma unroll
    for (int i = 0; i < 16; ++i) {
        int cc = tr + i * 4;
        float v = T[rr][cc];
        unsigned short h = f2bf(v);
        hi[(size_t)(c0 + cc) * R + r0 + rr] = h;
        lo[(size_t)(c0 + cc) * R + r0 + rr] = f2bf(v - bf2f(h));
    }
}

// ---------------------------------------------------------------------------
// Kernel 3: elementwise split-convert fp32 -> hi/lo bf16 (as ushort).
// ---------------------------------------------------------------------------
__global__ __launch_bounds__(256) void k_conv(const float* __restrict__ in,
                                              unsigned short* __restrict__ hi,
                                              unsigned short* __restrict__ lo,
                                              int n4) {
    int i = blockIdx.x * 256 + threadIdx.x;
    if (i >= n4) return;
    float4 v = ((const float4*)in)[i];
    ushort4 h, l;
    h.x = f2bf(v.x); l.x = f2bf(v.x - bf2f(h.x));
    h.y = f2bf(v.y); l.y = f2bf(v.y - bf2f(h.y));
    h.z = f2bf(v.z); l.z = f2bf(v.z - bf2f(h.z));
    h.w = f2bf(v.w); l.w = f2bf(v.w - bf2f(h.w));
    ((ushort4*)hi)[i] = h;
    ((ushort4*)lo)[i] = l;
}

// ---------------------------------------------------------------------------
// Kernel 4: bf16x3 GEMM producing QKV directly in attention-ready formats.
// A = x hi/lo [M][K]; B = wcatT hi/lo [1536][K] (pre-transposed).
// Epilogue: cols <1024 (Q,K): write hi/lo bf16 into qkh/qkl [M][1024].
//           cols >=1024 (V):  write bf16 TRANSPOSED into vT [512][M].
// ---------------------------------------------------------------------------
__global__ __launch_bounds__(256) void k_gemm_qkv(
        const unsigned short* __restrict__ Ahg, const unsigned short* __restrict__ Alg,
        const unsigned short* __restrict__ Bhg, const unsigned short* __restrict__ Blg,
        unsigned short* __restrict__ qkh, unsigned short* __restrict__ qkl,
        unsigned short* __restrict__ vT) {
    const int M = MROWS, K = DMODEL;
    __shared__ unsigned short Ah[128 * 32], Al[128 * 32];
    __shared__ unsigned short Bh[128 * 32], Bl[128 * 32];

    const int t  = threadIdx.x;
    const int m0 = blockIdx.x * 128, n0 = blockIdx.y * 128;
    const int w  = t >> 6, l = t & 63;
    const int wm = (w >> 1) * 64, wn = (w & 1) * 64;
    const int r  = l & 15, q = l >> 4;

    const int srow = t >> 2;
    const int skq  = (t & 3) * 8;
    const int soff = srow * 32 + skq;

    f32x4 acc[4][4] = {};

    for (int k0 = 0; k0 < K; k0 += 32) {
        __syncthreads();
        gl16(Ahg + (size_t)(m0 + srow) * K + k0 + skq,      &Ah[soff]);
        gl16(Ahg + (size_t)(m0 + 64 + srow) * K + k0 + skq, &Ah[soff + 64 * 32]);
        gl16(Alg + (size_t)(m0 + srow) * K + k0 + skq,      &Al[soff]);
        gl16(Alg + (size_t)(m0 + 64 + srow) * K + k0 + skq, &Al[soff + 64 * 32]);
        gl16(Bhg + (size_t)(n0 + srow) * K + k0 + skq,      &Bh[soff]);
        gl16(Bhg + (size_t)(n0 + 64 + srow) * K + k0 + skq, &Bh[soff + 64 * 32]);
        gl16(Blg + (size_t)(n0 + srow) * K + k0 + skq,      &Bl[soff]);
        gl16(Blg + (size_t)(n0 + 64 + srow) * K + k0 + skq, &Bl[soff + 64 * 32]);
        __syncthreads();

        short8 ah[4], al[4], bh[4], bl[4];
#pragma unroll
        for (int i = 0; i < 4; ++i) {
            ah[i] = *(const short8*)&Ah[(wm + i * 16 + r) * 32 + q * 8];
            al[i] = *(const short8*)&Al[(wm + i * 16 + r) * 32 + q * 8];
            bh[i] = *(const short8*)&Bh[(wn + i * 16 + r) * 32 + q * 8];
            bl[i] = *(const short8*)&Bl[(wn + i * 16 + r) * 32 + q * 8];
        }
#pragma unroll
        for (int i = 0; i < 4; ++i)
#pragma unroll
            for (int j = 0; j < 4; ++j) {
                acc[i][j] = __builtin_amdgcn_mfma_f32_16x16x32_bf16(ah[i], bh[j], acc[i][j], 0, 0, 0);
                acc[i][j] = __builtin_amdgcn_mfma_f32_16x16x32_bf16(al[i], bh[j], acc[i][j], 0, 0, 0);
                acc[i][j] = __builtin_amdgcn_mfma_f32_16x16x32_bf16(ah[i], bl[j], acc[i][j], 0, 0, 0);
            }
    }

    if (n0 < 1024) {   // Q,K columns -> hi/lo split, row-major
#pragma unroll
        for (int i = 0; i < 4; ++i)
#pragma unroll
            for (int j = 0; j < 4; ++j) {
                int col = n0 + wn + j * 16 + r;
                size_t rowb = (size_t)(m0 + wm + i * 16 + q * 4);
#pragma unroll
                for (int e = 0; e < 4; ++e) {
                    float v = acc[i][j][e];
                    unsigned short h = f2bf(v);
                    qkh[(rowb + e) * 1024 + col] = h;
                    qkl[(rowb + e) * 1024 + col] = f2bf(v - bf2f(h));
                }
            }
    } else {           // V columns -> bf16, transposed [d][row]
#pragma unroll
        for (int i = 0; i < 4; ++i)
#pragma unroll
            for (int j = 0; j < 4; ++j) {
                int d = n0 - 1024 + wn + j * 16 + r;
                size_t rowb = (size_t)(m0 + wm + i * 16 + q * 4);
                ushort4 pk;
                pk.x = f2bf(acc[i][j][0]); pk.y = f2bf(acc[i][j][1]);
                pk.z = f2bf(acc[i][j][2]); pk.w = f2bf(acc[i][j][3]);
                *(ushort4*)&vT[(size_t)d * MROWS + rowb] = pk;
            }
    }
}

// ---------------------------------------------------------------------------
// Kernel 5: MFMA flash attention.
// Block = 256 thr (4 waves x 16 q-rows) per (b, n, 64-q-tile).
// QK^T: bf16x3 (fp32-accurate scores), 16x16x32 MFMA; K hi/lo staged in LDS
// with 16B-block XOR swizzle (blk ^= row&7).  Softmax fully in-register via
// 16-lane shfl_xor reduces.  P -> per-wave LDS (row-permuted) -> exact B-frags
// via ds_read_b64_tr_b16.  PV: plain bf16, V^T staged like K.
// Output: z hi/lo bf16 [M][512] for the bf16x3 out-projection.
// ---------------------------------------------------------------------------
__global__ __launch_bounds__(256) void k_attn_mfma(
        const unsigned short* __restrict__ qkh, const unsigned short* __restrict__ qkl,
        const unsigned short* __restrict__ vT,
        unsigned short* __restrict__ zh, unsigned short* __restrict__ zl) {
    __shared__ unsigned short Ksh[64 * 64], Ksl[64 * 64], Vt[64 * 64];
    __shared__ unsigned short Pt[4 * 64 * 16];   // per-wave 2KB

    const int t  = threadIdx.x;
    const int w  = t >> 6, l = t & 63;
    const int qt = 31 - blockIdx.x;   // big tiles first
    const int n  = blockIdx.y, b = blockIdx.z;
    const int r  = l & 15, g = l >> 4;
    const int wq0 = w * 16;
    const size_t qrow0 = (size_t)(b * SLEN + qt * 64);

    // Q fragments (A operand), hoisted: rows wq0+r, k-chunks ks*32+g*8
    short8 qh[2], ql[2];
#pragma unroll
    for (int ks = 0; ks < 2; ++ks) {
        size_t off = (qrow0 + wq0 + r) * 1024 + n * 64 + ks * 32 + g * 8;
        qh[ks] = *(const short8*)(qkh + off);
        ql[ks] = *(const short8*)(qkl + off);
    }

    float m_[4], lsum[4];
#pragma unroll
    for (int e = 0; e < 4; ++e) { m_[e] = -3.0e38f; lsum[e] = 0.0f; }
    f32x4 accz[4] = {};   // z^T: 4 d-tiles x (4 rows, col q=r)

    const int sr = t >> 2, sb = t & 3;   // staging: row, block

    for (int kt = 0; kt <= qt; ++kt) {
        const size_t krow0 = (size_t)(b * SLEN + kt * 64);
        __syncthreads();
#pragma unroll
        for (int hf = 0; hf < 2; ++hf) {
            int bk = sb + hf * 4;
            size_t goff = (krow0 + sr) * 1024 + 512 + n * 64 + bk * 8;
            short8 kh8 = *(const short8*)(qkh + goff);
            short8 kl8 = *(const short8*)(qkl + goff);
            short8 v8  = *(const short8*)(vT + (size_t)(n * 64 + sr) * MROWS + krow0 + bk * 8);
            int swb = sr * 128 + ((bk ^ (sr & 7)) << 4);
            *(short8*)((char*)Ksh + swb) = kh8;
            *(short8*)((char*)Ksl + swb) = kl8;
            *(short8*)((char*)Vt + swb)  = v8;
        }
        __syncthreads();

        // S = Q.K^T (bf16x3), tile cols ct*16+r
        f32x4 s[4] = {};
#pragma unroll
        for (int ct = 0; ct < 4; ++ct)
#pragma unroll
            for (int ks = 0; ks < 2; ++ks) {
                int row = ct * 16 + r;
                int off = row * 128 + (((ks * 4 + g) ^ (row & 7)) << 4);
                short8 kh8 = *(const short8*)((char*)Ksh + off);
                short8 kl8 = *(const short8*)((char*)Ksl + off);
                s[ct] = __builtin_amdgcn_mfma_f32_16x16x32_bf16(qh[ks], kh8, s[ct], 0, 0, 0);
                s[ct] = __builtin_amdgcn_mfma_f32_16x16x32_bf16(ql[ks], kh8, s[ct], 0, 0, 0);
                s[ct] = __builtin_amdgcn_mfma_f32_16x16x32_bf16(qh[ks], kl8, s[ct], 0, 0, 0);
            }

        // scale + causal mask (only diagonal tile can mask)
#pragma unroll
        for (int ct = 0; ct < 4; ++ct)
#pragma unroll
            for (int e = 0; e < 4; ++e) {
                float sv = s[ct][e] * 0.125f;
                if (kt == qt && (ct * 16 + r) > (wq0 + g * 4 + e))
                    sv = -100000.0f;   // reference IGNORE
                s[ct][e] = sv;
            }

        // online softmax: row max (rows wq0+g*4+e live on 16-lane group g)
        float al[4], nm[4];
#pragma unroll
        for (int e = 0; e < 4; ++e) {
            float pm = fmaxf(fmaxf(s[0][e], s[1][e]), fmaxf(s[2][e], s[3][e]));
            pm = fmaxf(pm, __shfl_xor(pm, 1));
            pm = fmaxf(pm, __shfl_xor(pm, 2));
            pm = fmaxf(pm, __shfl_xor(pm, 4));
            pm = fmaxf(pm, __shfl_xor(pm, 8));
            nm[e] = fmaxf(m_[e], pm);
            al[e] = __expf(m_[e] - nm[e]);
            m_[e] = nm[e];
        }

        // P = exp(S-m), pack bf16, write P^T to per-wave LDS (permuted rows
        // so ds_read_b64_tr_b16 yields exact 16x16x32 B-fragments)
        float ps[4] = {};
#pragma unroll
        for (int ct = 0; ct < 4; ++ct) {
            float p0 = __expf(s[ct][0] - nm[0]);
            float p1 = __expf(s[ct][1] - nm[1]);
            float p2 = __expf(s[ct][2] - nm[2]);
            float p3 = __expf(s[ct][3] - nm[3]);
            ps[0] += p0; ps[1] += p1; ps[2] += p2; ps[3] += p3;
            short4v pk = { (short)f2bf(p0), (short)f2bf(p1),
                           (short)f2bf(p2), (short)f2bf(p3) };
            int kv = ct * 16 + r;
            int phys = (kv >> 5) * 32 + (((kv >> 2) & 1) << 4)
                     + (((kv >> 3) & 3) << 2) + (kv & 3);
            *(short4v*)((char*)Pt + w * 2048 + phys * 32 + g * 8) = pk;
        }

        // row sums -> lsum
#pragma unroll
        for (int e = 0; e < 4; ++e) {
            float rs = ps[e];
            rs += __shfl_xor(rs, 1); rs += __shfl_xor(rs, 2);
            rs += __shfl_xor(rs, 4); rs += __shfl_xor(rs, 8);
            lsum[e] = lsum[e] * al[e] + rs;
        }

        // alpha for this lane's accumulator column q=r (wave transpose)
        int src = (r >> 2) << 4;
        float a0 = __shfl(al[0], src), a1 = __shfl(al[1], src);
        float a2 = __shfl(al[2], src), a3 = __shfl(al[3], src);
        float ax = (r & 1) ? a1 : a0, ay = (r & 1) ? a3 : a2;
        float aq = (r & 2) ? ay : ax;
#pragma unroll
        for (int dt = 0; dt < 4; ++dt) {
            accz[dt][0] *= aq; accz[dt][1] *= aq;
            accz[dt][2] *= aq; accz[dt][3] *= aq;
        }

        // PV: z^T += V^T . P^T   (wave-private P; drain writes, then tr-read)
        asm volatile("s_waitcnt lgkmcnt(0)" ::: "memory");
        __builtin_amdgcn_sched_barrier(0);
#pragma unroll
        for (int ks = 0; ks < 2; ++ks) {
            unsigned base = (unsigned)(size_t)((char*)Pt + w * 2048 + ks * 1024) + l * 8;
            U64S4 t1, t2;
            asm volatile("ds_read_b64_tr_b16 %0, %1" : "=v"(t1.u) : "v"(base) : "memory");
            asm volatile("ds_read_b64_tr_b16 %0, %1" : "=v"(t2.u) : "v"(base + 512) : "memory");
            asm volatile("s_waitcnt lgkmcnt(0)" ::: "memory");
            __builtin_amdgcn_sched_barrier(0);
            short8 pfrag = { t1.s[0], t1.s[1], t1.s[2], t1.s[3],
                             t2.s[0], t2.s[1], t2.s[2], t2.s[3] };
#pragma unroll
            for (int dt = 0; dt < 4; ++dt) {
                int row = dt * 16 + r;
                int off = row * 128 + (((ks * 4 + g) ^ (row & 7)) << 4);
                short8 vfrag = *(const short8*)((char*)Vt + off);
                accz[dt] = __builtin_amdgcn_mfma_f32_16x16x32_bf16(vfrag, pfrag, accz[dt], 0, 0, 0);
            }
        }
    }

    // normalize (1/l for q=r via wave transpose), write z hi/lo
    int src = (r >> 2) << 4;
    float l0 = __shfl(lsum[0], src), l1 = __shfl(lsum[1], src);
    float l2 = __shfl(lsum[2], src), l3 = __shfl(lsum[3], src);
    float lx = (r & 1) ? l1 : l0, ly = (r & 1) ? l3 : l2;
    float inv = 1.0f / ((r & 2) ? ly : lx);
#pragma unroll
    for (int dt = 0; dt < 4; ++dt) {
        ushort4 h4, l4;
#pragma unroll
        for (int e = 0; e < 4; ++e) {
            float z = accz[dt][e] * inv;
            unsigned short hh = f2bf(z);
            ((unsigned short*)&h4)[e] = hh;
            ((unsigned short*)&l4)[e] = f2bf(z - bf2f(hh));
        }
        size_t off = (qrow0 + wq0 + r) * 512 + n * 64 + dt * 16 + g * 4;
        *(ushort4*)(zh + off) = h4;
        *(ushort4*)(zl + off) = l4;
    }
}

// ---------------------------------------------------------------------------
// Kernel 6: bf16x3 GEMM (unchanged R3) for the output projection.
// ---------------------------------------------------------------------------
__global__ __launch_bounds__(256) void k_gemm_b3(
        const unsigned short* __restrict__ Ahg, const unsigned short* __restrict__ Alg,
        const unsigned short* __restrict__ Bhg, const unsigned short* __restrict__ Blg,
        float* __restrict__ C, int M, int N, int K) {
    __shared__ unsigned short Ah[128 * 32], Al[128 * 32];
    __shared__ unsigned short Bh[128 * 32], Bl[128 * 32];

    const int t  = threadIdx.x;
    const int m0 = blockIdx.x * 128, n0 = blockIdx.y * 128;
    const int w  = t >> 6, l = t & 63;
    const int wm = (w >> 1) * 64, wn = (w & 1) * 64;
    const int r  = l & 15, q = l >> 4;

    const int srow = t >> 2;
    const int skq  = (t & 3) * 8;
    const int soff = srow * 32 + skq;

    f32x4 acc[4][4] = {};

    for (int k0 = 0; k0 < K; k0 += 32) {
        __syncthreads();
        gl16(Ahg + (size_t)(m0 + srow) * K + k0 + skq,      &Ah[soff]);
        gl16(Ahg + (size_t)(m0 + 64 + srow) * K + k0 + skq, &Ah[soff + 64 * 32]);
        gl16(Alg + (size_t)(m0 + srow) * K + k0 + skq,      &Al[soff]);
        gl16(Alg + (size_t)(m0 + 64 + srow) * K + k0 + skq, &Al[soff + 64 * 32]);
        gl16(Bhg + (size_t)(n0 + srow) * K + k0 + skq,      &Bh[soff]);
        gl16(Bhg + (size_t)(n0 + 64 + srow) * K + k0 + skq, &Bh[soff + 64 * 32]);
        gl16(Blg + (size_t)(n0 + srow) * K + k0 + skq,      &Bl[soff]);
        gl16(Blg + (size_t)(n0 + 64 + srow) * K + k0 + skq, &Bl[soff + 64 * 32]);
        __syncthreads();

        short8 ah[4], al[4], bh[4], bl[4];
#pragma unroll
        for (int i = 0; i < 4; ++i) {
            ah[i] = *(const short8*)&Ah[(wm + i * 16 + r) * 32 + q * 8];
            al[i] = *(const short8*)&Al[(wm + i * 16 + r) * 32 + q * 8];
            bh[i] = *(const short8*)&Bh[(wn + i * 16 + r) * 32 + q * 8];
            bl[i] = *(const short8*)&Bl[(wn + i * 16 + r) * 32 + q * 8];
        }
#pragma unroll
        for (int i = 0; i < 4; ++i)
#pragma unroll
            for (int j = 0; j < 4; ++j) {
                acc[i][j] = __builtin_amdgcn_mfma_f32_16x16x32_bf16(ah[i], bh[j], acc[i][j], 0, 0, 0);
                acc[i][j] = __builtin_amdgcn_mfma_f32_16x16x32_bf16(al[i], bh[j], acc[i][j], 0, 0, 0);
                acc[i][j] = __builtin_amdgcn_mfma_f32_16x16x32_bf16(ah[i], bl[j], acc[i][j], 0, 0, 0);
            }
    }

#pragma unroll
    for (int i = 0; i < 4; ++i)
#pragma unroll
        for (int j = 0; j < 4; ++j) {
            int col = n0 + wn + j * 16 + r;
            size_t rowb = (size_t)(m0 + wm + i * 16 + q * 4);
#pragma unroll
            for (int e = 0; e < 4; ++e)
                C[(rowb + e) * N + col] = acc[i][j][e];
        }
}

// ---------------------------------------------------------------------------
// Workspace (bytes, 120 MB total):
//   0        : xh 32M      -> after gemm1: zh 8M (at 0), zl 8M (at 8M)
//   32M      : xl 32M
//   64M      : qkh 16M     (first 12M doubles as wcat fp32 before gemm1)
//   80M      : qkl 16M
//   96M      : vT   8M
//   104M     : wcatTh 6M   110M: wcatTl 6M   116M: woTh 2M   118M: woTl 2M
// ---------------------------------------------------------------------------
extern "C" void kernel_launch(void* const* d_in, const int* in_sizes, int n_in,
                              void* d_out, int out_size, void* d_ws, size_t ws_size,
                              hipStream_t stream) {
    const float* x  = (const float*)d_in[0];
    const float* wq = (const float*)d_in[1];
    const float* wk = (const float*)d_in[2];
    const float* wv = (const float*)d_in[3];
    const float* wo = (const float*)d_in[4];
    float* out = (float*)d_out;

    char* w = (char*)d_ws;
    unsigned short* xh = (unsigned short*)(w);
    unsigned short* xl = (unsigned short*)(w + 33554432);
    unsigned short* zh = (unsigned short*)(w);
    unsigned short* zl = (unsigned short*)(w + 8388608);
    unsigned short* qkh = (unsigned short*)(w + 67108864);
    unsigned short* qkl = (unsigned short*)(w + 83886080);
    unsigned short* vT  = (unsigned short*)(w + 100663296);
    float*          wcat   = (float*)(w + 67108864);
    unsigned short* wcatTh = (unsigned short*)(w + 109051904);
    unsigned short* wcatTl = (unsigned short*)(w + 115343360);
    unsigned short* woTh   = (unsigned short*)(w + 121634816);
    unsigned short* woTl   = (unsigned short*)(w + 123731968);

    k_pack<<<dim3((DMODEL * QKV + 255) / 256), 256, 0, stream>>>(wq, wk, wv, wcat);
    k_transconv<<<dim3(32, 24), 256, 0, stream>>>(wcat, wcatTh, wcatTl, DMODEL, QKV);
    k_transconv<<<dim3(8, 32), 256, 0, stream>>>(wo, woTh, woTl, KVDIM, DMODEL);
    k_conv<<<dim3(16384), 256, 0, stream>>>(x, xh, xl, MROWS * DMODEL / 4);
    k_gemm_qkv<<<dim3(64, 12), 256, 0, stream>>>(xh, xl, wcatTh, wcatTl,
                                                 qkh, qkl, vT);
    k_attn_mfma<<<dim3(32, NKV, BATCH), 256, 0, stream>>>(qkh, qkl, vT, zh, zl);
    k_gemm_b3<<<dim3(64, 16), 256, 0, stream>>>(zh, zl, woTh, woTl, out,
                                                MROWS, DMODEL, KVDIM);
}

// Round 5
// 431.888 us; speedup vs baseline: 4.8678x; 1.0171x over previous
//
#include <hip/hip_runtime.h>

typedef __attribute__((ext_vector_type(8))) short short8;
typedef __attribute__((ext_vector_type(4))) short short4v;
typedef __attribute__((ext_vector_type(4))) float f32x4;

#define BATCH  4
#define SLEN   2048
#define DMODEL 2048
#define NKV    8
#define GRP    4
#define DH     64
#define QKV    1536
#define KVDIM  512
#define MROWS  (BATCH * SLEN)   // 8192

// ---- bf16 helpers (RNE) ----------------------------------------------------
__device__ __forceinline__ unsigned short f2bf(float f) {
    unsigned u = __float_as_uint(f);
    u += 0x7FFFu + ((u >> 16) & 1u);
    return (unsigned short)(u >> 16);
}
__device__ __forceinline__ float bf2f(unsigned short h) {
    return __uint_as_float(((unsigned)h) << 16);
}

// ---- async global->LDS, 16B per lane ---------------------------------------
__device__ __forceinline__ void gl16(const void* g, void* l) {
    __builtin_amdgcn_global_load_lds(
        (const __attribute__((address_space(1))) void*)g,
        (__attribute__((address_space(3))) void*)l, 16, 0, 0);
}

union U64S4 { unsigned long long u; short4v s; };

// ---------------------------------------------------------------------------
// Kernel 1: pack weights into Wcat[d_model][1536] (fp32).
// ---------------------------------------------------------------------------
__global__ __launch_bounds__(256) void k_pack(const float* __restrict__ wq,
                                              const float* __restrict__ wk,
                                              const float* __restrict__ wv,
                                              float* __restrict__ wcat) {
    int i = blockIdx.x * 256 + threadIdx.x;
    if (i >= DMODEL * QKV) return;
    int d = i / QKV, c = i - d * QKV;
    int mat = c >> 9, rem = c & 511;
    int n = rem >> 6, h = rem & 63;
    float val;
    if (mat == 0) {
        val = 0.0f;
#pragma unroll
        for (int g = 0; g < GRP; ++g)
            val += wq[((size_t)(n * GRP + g) * DMODEL + d) * DH + h];
    } else if (mat == 1) {
        val = wk[((size_t)n * DMODEL + d) * DH + h];
    } else {
        val = wv[((size_t)n * DMODEL + d) * DH + h];
    }
    wcat[(size_t)d * QKV + c] = val;
}

// ---------------------------------------------------------------------------
// Kernel 2: transpose + split-convert. in fp32 [R][C] -> hi/lo ushort [C][R].
// ---------------------------------------------------------------------------
__global__ __launch_bounds__(256) void k_transconv(const float* __restrict__ in,
                                                   unsigned short* __restrict__ hi,
                                                   unsigned short* __restrict__ lo,
                                                   int R, int C) {
    __shared__ float T[64][65];
    const int r0 = blockIdx.x * 64, c0 = blockIdx.y * 64;
    const int tr = threadIdx.x >> 6, tc = threadIdx.x & 63;
#pragma unroll
    for (int i = 0; i < 16; ++i)
        T[tr + i * 4][tc] = in[(size_t)(r0 + tr + i * 4) * C + c0 + tc];
    __syncthreads();
    const int rr = tc;
#pragma unroll
    for (int i = 0; i < 16; ++i) {
        int cc = tr + i * 4;
        float v = T[rr][cc];
        unsigned short h = f2bf(v);
        hi[(size_t)(c0 + cc) * R + r0 + rr] = h;
        lo[(size_t)(c0 + cc) * R + r0 + rr] = f2bf(v - bf2f(h));
    }
}

// ---------------------------------------------------------------------------
// Kernel 3: elementwise split-convert fp32 -> hi/lo bf16 (as ushort).
// ---------------------------------------------------------------------------
__global__ __launch_bounds__(256) void k_conv(const float* __restrict__ in,
                                              unsigned short* __restrict__ hi,
                                              unsigned short* __restrict__ lo,
                                              int n4) {
    int i = blockIdx.x * 256 + threadIdx.x;
    if (i >= n4) return;
    float4 v = ((const float4*)in)[i];
    ushort4 h, l;
    h.x = f2bf(v.x); l.x = f2bf(v.x - bf2f(h.x));
    h.y = f2bf(v.y); l.y = f2bf(v.y - bf2f(h.y));
    h.z = f2bf(v.z); l.z = f2bf(v.z - bf2f(h.z));
    h.w = f2bf(v.w); l.w = f2bf(v.w - bf2f(h.w));
    ((ushort4*)hi)[i] = h;
    ((ushort4*)lo)[i] = l;
}

// ---------------------------------------------------------------------------
// bf16x3 GEMM core, 2-phase pipelined (T3-min + T4 + T5 + T2 swizzle).
// LDS tile per matrix: [128 rows][64 cols bf16] = 128B rows = 8 x 16B blocks;
// cols 0..31 = hi, 32..63 = lo.  Physical 16B-block = logical ^ (row&7)
// (applied on the GLOBAL SOURCE address; global_load_lds dest stays linear;
// ds_read compensates) -> every bank exactly 2-way (free).
// Double-buffered (64KB total, 2 blocks/CU); one raw s_barrier per K-step;
// stage for t+1 issued BEFORE compute of t, drained at end of t.
// ---------------------------------------------------------------------------
__device__ __forceinline__ void stage_pair(
        const unsigned short* __restrict__ Hg, const unsigned short* __restrict__ Lg,
        unsigned short* lds, int t, size_t grow0, int K, int k0) {
#pragma unroll
    for (int j = 0; j < 4; ++j) {
        int slot = j * 256 + t;
        int row = slot >> 3, blk = slot & 7;
        int c = blk ^ (row & 7);   // logical chunk held by this physical slot
        const unsigned short* src = (c < 4)
            ? Hg + (grow0 + row) * (size_t)K + k0 + c * 8
            : Lg + (grow0 + row) * (size_t)K + k0 + (c - 4) * 8;
        gl16(src, lds + slot * 8);
    }
}

#define GEMM_B3_MAINLOOP(Ahg, Alg, Bhg, Blg, K_, m0_, n0_)                    \
    const int NT = (K_) / 32;                                                 \
    stage_pair(Ahg, Alg, A2[0], t, m0_, K_, 0);                               \
    stage_pair(Bhg, Blg, B2[0], t, n0_, K_, 0);                               \
    asm volatile("s_waitcnt vmcnt(0)" ::: "memory");                          \
    __builtin_amdgcn_s_barrier();                                             \
    int cur = 0;                                                              \
    for (int kt = 0; kt < NT; ++kt) {                                         \
        if (kt + 1 < NT) {                                                    \
            stage_pair(Ahg, Alg, A2[cur ^ 1], t, m0_, K_, (kt + 1) * 32);     \
            stage_pair(Bhg, Blg, B2[cur ^ 1], t, n0_, K_, (kt + 1) * 32);     \
        }                                                                     \
        const unsigned short* Ab = A2[cur];                                   \
        const unsigned short* Bb = B2[cur];                                   \
        short8 ah[4], al[4], bh[4], bl[4];                                    \
        _Pragma("unroll")                                                     \
        for (int i = 0; i < 4; ++i) {                                         \
            int ra = wm + i * 16 + r, rb = wn + i * 16 + r;                   \
            ah[i] = *(const short8*)&Ab[ra * 64 + ((q ^ (ra & 7)) << 3)];     \
            al[i] = *(const short8*)&Ab[ra * 64 + (((q ^ 4) ^ (ra & 7)) << 3)]; \
            bh[i] = *(const short8*)&Bb[rb * 64 + ((q ^ (rb & 7)) << 3)];     \
            bl[i] = *(const short8*)&Bb[rb * 64 + (((q ^ 4) ^ (rb & 7)) << 3)]; \
        }                                                                     \
        __builtin_amdgcn_s_setprio(1);                                        \
        _Pragma("unroll")                                                     \
        for (int i = 0; i < 4; ++i)                                           \
            _Pragma("unroll")                                                 \
            for (int j = 0; j < 4; ++j) {                                     \
                acc[i][j] = __builtin_amdgcn_mfma_f32_16x16x32_bf16(ah[i], bh[j], acc[i][j], 0, 0, 0); \
                acc[i][j] = __builtin_amdgcn_mfma_f32_16x16x32_bf16(al[i], bh[j], acc[i][j], 0, 0, 0); \
                acc[i][j] = __builtin_amdgcn_mfma_f32_16x16x32_bf16(ah[i], bl[j], acc[i][j], 0, 0, 0); \
            }                                                                 \
        __builtin_amdgcn_s_setprio(0);                                        \
        asm volatile("s_waitcnt vmcnt(0)" ::: "memory");                      \
        __builtin_amdgcn_s_barrier();                                         \
        cur ^= 1;                                                             \
    }

// ---------------------------------------------------------------------------
// Kernel 4: bf16x3 GEMM producing QKV in attention-ready formats.
// ---------------------------------------------------------------------------
__global__ __launch_bounds__(256) void k_gemm_qkv(
        const unsigned short* __restrict__ Ahg, const unsigned short* __restrict__ Alg,
        const unsigned short* __restrict__ Bhg, const unsigned short* __restrict__ Blg,
        unsigned short* __restrict__ qkh, unsigned short* __restrict__ qkl,
        unsigned short* __restrict__ vT) {
    __shared__ unsigned short A2[2][128 * 64];
    __shared__ unsigned short B2[2][128 * 64];

    const int t  = threadIdx.x;
    const size_t m0 = (size_t)blockIdx.x * 128, n0 = (size_t)blockIdx.y * 128;
    const int w  = t >> 6, l = t & 63;
    const int wm = (w >> 1) * 64, wn = (w & 1) * 64;
    const int r  = l & 15, q = l >> 4;

    f32x4 acc[4][4] = {};

    GEMM_B3_MAINLOOP(Ahg, Alg, Bhg, Blg, DMODEL, m0, n0)

    if (n0 < 1024) {   // Q,K columns -> hi/lo split, row-major
#pragma unroll
        for (int i = 0; i < 4; ++i)
#pragma unroll
            for (int j = 0; j < 4; ++j) {
                int col = (int)n0 + wn + j * 16 + r;
                size_t rowb = m0 + wm + i * 16 + q * 4;
#pragma unroll
                for (int e = 0; e < 4; ++e) {
                    float v = acc[i][j][e];
                    unsigned short h = f2bf(v);
                    qkh[(rowb + e) * 1024 + col] = h;
                    qkl[(rowb + e) * 1024 + col] = f2bf(v - bf2f(h));
                }
            }
    } else {           // V columns -> bf16, transposed [d][row]
#pragma unroll
        for (int i = 0; i < 4; ++i)
#pragma unroll
            for (int j = 0; j < 4; ++j) {
                int d = (int)n0 - 1024 + wn + j * 16 + r;
                size_t rowb = m0 + wm + i * 16 + q * 4;
                ushort4 pk;
                pk.x = f2bf(acc[i][j][0]); pk.y = f2bf(acc[i][j][1]);
                pk.z = f2bf(acc[i][j][2]); pk.w = f2bf(acc[i][j][3]);
                *(ushort4*)&vT[(size_t)d * MROWS + rowb] = pk;
            }
    }
}

// ---------------------------------------------------------------------------
// Kernel 6: bf16x3 GEMM, plain fp32 C output (output projection).
// ---------------------------------------------------------------------------
__global__ __launch_bounds__(256) void k_gemm_b3(
        const unsigned short* __restrict__ Ahg, const unsigned short* __restrict__ Alg,
        const unsigned short* __restrict__ Bhg, const unsigned short* __restrict__ Blg,
        float* __restrict__ C, int M, int N, int K) {
    __shared__ unsigned short A2[2][128 * 64];
    __shared__ unsigned short B2[2][128 * 64];

    const int t  = threadIdx.x;
    const size_t m0 = (size_t)blockIdx.x * 128, n0 = (size_t)blockIdx.y * 128;
    const int w  = t >> 6, l = t & 63;
    const int wm = (w >> 1) * 64, wn = (w & 1) * 64;
    const int r  = l & 15, q = l >> 4;

    f32x4 acc[4][4] = {};

    GEMM_B3_MAINLOOP(Ahg, Alg, Bhg, Blg, K, m0, n0)

#pragma unroll
    for (int i = 0; i < 4; ++i)
#pragma unroll
        for (int j = 0; j < 4; ++j) {
            int col = (int)n0 + wn + j * 16 + r;
            size_t rowb = m0 + wm + i * 16 + q * 4;
#pragma unroll
            for (int e = 0; e < 4; ++e)
                C[(rowb + e) * N + col] = acc[i][j][e];
        }
}

// ---------------------------------------------------------------------------
// Kernel 5: MFMA flash attention (unchanged from R4).
// ---------------------------------------------------------------------------
__global__ __launch_bounds__(256) void k_attn_mfma(
        const unsigned short* __restrict__ qkh, const unsigned short* __restrict__ qkl,
        const unsigned short* __restrict__ vT,
        unsigned short* __restrict__ zh, unsigned short* __restrict__ zl) {
    __shared__ unsigned short Ksh[64 * 64], Ksl[64 * 64], Vt[64 * 64];
    __shared__ unsigned short Pt[4 * 64 * 16];   // per-wave 2KB

    const int t  = threadIdx.x;
    const int w  = t >> 6, l = t & 63;
    const int qt = 31 - blockIdx.x;   // big tiles first
    const int n  = blockIdx.y, b = blockIdx.z;
    const int r  = l & 15, g = l >> 4;
    const int wq0 = w * 16;
    const size_t qrow0 = (size_t)(b * SLEN + qt * 64);

    short8 qh[2], ql[2];
#pragma unroll
    for (int ks = 0; ks < 2; ++ks) {
        size_t off = (qrow0 + wq0 + r) * 1024 + n * 64 + ks * 32 + g * 8;
        qh[ks] = *(const short8*)(qkh + off);
        ql[ks] = *(const short8*)(qkl + off);
    }

    float m_[4], lsum[4];
#pragma unroll
    for (int e = 0; e < 4; ++e) { m_[e] = -3.0e38f; lsum[e] = 0.0f; }
    f32x4 accz[4] = {};

    const int sr = t >> 2, sb = t & 3;

    for (int kt = 0; kt <= qt; ++kt) {
        const size_t krow0 = (size_t)(b * SLEN + kt * 64);
        __syncthreads();
#pragma unroll
        for (int hf = 0; hf < 2; ++hf) {
            int bk = sb + hf * 4;
            size_t goff = (krow0 + sr) * 1024 + 512 + n * 64 + bk * 8;
            short8 kh8 = *(const short8*)(qkh + goff);
            short8 kl8 = *(const short8*)(qkl + goff);
            short8 v8  = *(const short8*)(vT + (size_t)(n * 64 + sr) * MROWS + krow0 + bk * 8);
            int swb = sr * 128 + ((bk ^ (sr & 7)) << 4);
            *(short8*)((char*)Ksh + swb) = kh8;
            *(short8*)((char*)Ksl + swb) = kl8;
            *(short8*)((char*)Vt + swb)  = v8;
        }
        __syncthreads();

        f32x4 s[4] = {};
#pragma unroll
        for (int ct = 0; ct < 4; ++ct)
#pragma unroll
            for (int ks = 0; ks < 2; ++ks) {
                int row = ct * 16 + r;
                int off = row * 128 + (((ks * 4 + g) ^ (row & 7)) << 4);
                short8 kh8 = *(const short8*)((char*)Ksh + off);
                short8 kl8 = *(const short8*)((char*)Ksl + off);
                s[ct] = __builtin_amdgcn_mfma_f32_16x16x32_bf16(qh[ks], kh8, s[ct], 0, 0, 0);
                s[ct] = __builtin_amdgcn_mfma_f32_16x16x32_bf16(ql[ks], kh8, s[ct], 0, 0, 0);
                s[ct] = __builtin_amdgcn_mfma_f32_16x16x32_bf16(qh[ks], kl8, s[ct], 0, 0, 0);
            }

#pragma unroll
        for (int ct = 0; ct < 4; ++ct)
#pragma unroll
            for (int e = 0; e < 4; ++e) {
                float sv = s[ct][e] * 0.125f;
                if (kt == qt && (ct * 16 + r) > (wq0 + g * 4 + e))
                    sv = -100000.0f;
                s[ct][e] = sv;
            }

        float al[4], nm[4];
#pragma unroll
        for (int e = 0; e < 4; ++e) {
            float pm = fmaxf(fmaxf(s[0][e], s[1][e]), fmaxf(s[2][e], s[3][e]));
            pm = fmaxf(pm, __shfl_xor(pm, 1));
            pm = fmaxf(pm, __shfl_xor(pm, 2));
            pm = fmaxf(pm, __shfl_xor(pm, 4));
            pm = fmaxf(pm, __shfl_xor(pm, 8));
            nm[e] = fmaxf(m_[e], pm);
            al[e] = __expf(m_[e] - nm[e]);
            m_[e] = nm[e];
        }

        float ps[4] = {};
#pragma unroll
        for (int ct = 0; ct < 4; ++ct) {
            float p0 = __expf(s[ct][0] - nm[0]);
            float p1 = __expf(s[ct][1] - nm[1]);
            float p2 = __expf(s[ct][2] - nm[2]);
            float p3 = __expf(s[ct][3] - nm[3]);
            ps[0] += p0; ps[1] += p1; ps[2] += p2; ps[3] += p3;
            short4v pk = { (short)f2bf(p0), (short)f2bf(p1),
                           (short)f2bf(p2), (short)f2bf(p3) };
            int kv = ct * 16 + r;
            int phys = (kv >> 5) * 32 + (((kv >> 2) & 1) << 4)
                     + (((kv >> 3) & 3) << 2) + (kv & 3);
            *(short4v*)((char*)Pt + w * 2048 + phys * 32 + g * 8) = pk;
        }

#pragma unroll
        for (int e = 0; e < 4; ++e) {
            float rs = ps[e];
            rs += __shfl_xor(rs, 1); rs += __shfl_xor(rs, 2);
            rs += __shfl_xor(rs, 4); rs += __shfl_xor(rs, 8);
            lsum[e] = lsum[e] * al[e] + rs;
        }

        int src = (r >> 2) << 4;
        float a0 = __shfl(al[0], src), a1 = __shfl(al[1], src);
        float a2 = __shfl(al[2], src), a3 = __shfl(al[3], src);
        float ax = (r & 1) ? a1 : a0, ay = (r & 1) ? a3 : a2;
        float aq = (r & 2) ? ay : ax;
#pragma unroll
        for (int dt = 0; dt < 4; ++dt) {
            accz[dt][0] *= aq; accz[dt][1] *= aq;
            accz[dt][2] *= aq; accz[dt][3] *= aq;
        }

        asm volatile("s_waitcnt lgkmcnt(0)" ::: "memory");
        __builtin_amdgcn_sched_barrier(0);
#pragma unroll
        for (int ks = 0; ks < 2; ++ks) {
            unsigned base = (unsigned)(size_t)((char*)Pt + w * 2048 + ks * 1024) + l * 8;
            U64S4 t1, t2;
            asm volatile("ds_read_b64_tr_b16 %0, %1" : "=v"(t1.u) : "v"(base) : "memory");
            asm volatile("ds_read_b64_tr_b16 %0, %1" : "=v"(t2.u) : "v"(base + 512) : "memory");
            asm volatile("s_waitcnt lgkmcnt(0)" ::: "memory");
            __builtin_amdgcn_sched_barrier(0);
            short8 pfrag = { t1.s[0], t1.s[1], t1.s[2], t1.s[3],
                             t2.s[0], t2.s[1], t2.s[2], t2.s[3] };
#pragma unroll
            for (int dt = 0; dt < 4; ++dt) {
                int row = dt * 16 + r;
                int off = row * 128 + (((ks * 4 + g) ^ (row & 7)) << 4);
                short8 vfrag = *(const short8*)((char*)Vt + off);
                accz[dt] = __builtin_amdgcn_mfma_f32_16x16x32_bf16(vfrag, pfrag, accz[dt], 0, 0, 0);
            }
        }
    }

    int src = (r >> 2) << 4;
    float l0 = __shfl(lsum[0], src), l1 = __shfl(lsum[1], src);
    float l2 = __shfl(lsum[2], src), l3 = __shfl(lsum[3], src);
    float lx = (r & 1) ? l1 : l0, ly = (r & 1) ? l3 : l2;
    float inv = 1.0f / ((r & 2) ? ly : lx);
#pragma unroll
    for (int dt = 0; dt < 4; ++dt) {
        ushort4 h4, l4;
#pragma unroll
        for (int e = 0; e < 4; ++e) {
            float z = accz[dt][e] * inv;
            unsigned short hh = f2bf(z);
            ((unsigned short*)&h4)[e] = hh;
            ((unsigned short*)&l4)[e] = f2bf(z - bf2f(hh));
        }
        size_t off = (qrow0 + wq0 + r) * 512 + n * 64 + dt * 16 + g * 4;
        *(ushort4*)(zh + off) = h4;
        *(ushort4*)(zl + off) = l4;
    }
}

// ---------------------------------------------------------------------------
// Workspace (bytes, 120 MB total):
//   0        : xh 32M      -> after gemm1: zh 8M (at 0), zl 8M (at 8M)
//   32M      : xl 32M
//   64M      : qkh 16M     (first 12M doubles as wcat fp32 before gemm1)
//   80M      : qkl 16M
//   96M      : vT   8M
//   104M     : wcatTh 6M   110M: wcatTl 6M   116M: woTh 2M   118M: woTl 2M
// ---------------------------------------------------------------------------
extern "C" void kernel_launch(void* const* d_in, const int* in_sizes, int n_in,
                              void* d_out, int out_size, void* d_ws, size_t ws_size,
                              hipStream_t stream) {
    const float* x  = (const float*)d_in[0];
    const float* wq = (const float*)d_in[1];
    const float* wk = (const float*)d_in[2];
    const float* wv = (const float*)d_in[3];
    const float* wo = (const float*)d_in[4];
    float* out = (float*)d_out;

    char* w = (char*)d_ws;
    unsigned short* xh = (unsigned short*)(w);
    unsigned short* xl = (unsigned short*)(w + 33554432);
    unsigned short* zh = (unsigned short*)(w);
    unsigned short* zl = (unsigned short*)(w + 8388608);
    unsigned short* qkh = (unsigned short*)(w + 67108864);
    unsigned short* qkl = (unsigned short*)(w + 83886080);
    unsigned short* vT  = (unsigned short*)(w + 100663296);
    float*          wcat   = (float*)(w + 67108864);
    unsigned short* wcatTh = (unsigned short*)(w + 109051904);
    unsigned short* wcatTl = (unsigned short*)(w + 115343360);
    unsigned short* woTh   = (unsigned short*)(w + 121634816);
    unsigned short* woTl   = (unsigned short*)(w + 123731968);

    k_pack<<<dim3((DMODEL * QKV + 255) / 256), 256, 0, stream>>>(wq, wk, wv, wcat);
    k_transconv<<<dim3(32, 24), 256, 0, stream>>>(wcat, wcatTh, wcatTl, DMODEL, QKV);
    k_transconv<<<dim3(8, 32), 256, 0, stream>>>(wo, woTh, woTl, KVDIM, DMODEL);
    k_conv<<<dim3(16384), 256, 0, stream>>>(x, xh, xl, MROWS * DMODEL / 4);
    k_gemm_qkv<<<dim3(64, 12), 256, 0, stream>>>(xh, xl, wcatTh, wcatTl,
                                                 qkh, qkl, vT);
    k_attn_mfma<<<dim3(32, NKV, BATCH), 256, 0, stream>>>(qkh, qkl, vT, zh, zl);
    k_gemm_b3<<<dim3(64, 16), 256, 0, stream>>>(zh, zl, woTh, woTl, out,
                                                MROWS, DMODEL, KVDIM);
}